// Round 1
// baseline (461.939 us; speedup 1.0000x reference)
//
#include <hip/hip_runtime.h>
#include <hip/hip_bf16.h>

// Haar wavelet transform: x (B=16, C=64, H=512, W=512) f32 ->
// 4 outputs (LL, LH, HL, HH), each (16, 64, 256, 256) f32, concatenated in d_out.
//
// Each thread handles one float2 of output per plane: reads a float4 from two
// adjacent input rows (covers a 2(h) x 4(w) input patch = 2 output columns),
// writes float2 to each of the 4 output planes.

#define B_ 16
#define C_ 64
#define H_ 512
#define W_ 512
#define HO (H_/2)
#define WO (W_/2)
// output plane element count
#define NPLANE (B_*C_*HO*WO)          // 67,108,864
// work units: one per float2 of output
#define W2 (WO/2)                     // 128 float2 per output row
#define NWORK (B_*C_*HO*W2)           // 33,554,432

__global__ __launch_bounds__(256) void haar_kernel(const float* __restrict__ x,
                                                   float* __restrict__ out) {
    const long long stride = (long long)gridDim.x * blockDim.x;
    for (long long idx = (long long)blockIdx.x * blockDim.x + threadIdx.x;
         idx < (long long)NWORK; idx += stride) {
        // decompose: idx -> (bc, h, w2)
        const int w2 = (int)(idx & (W2 - 1));        // 0..127
        long long rest = idx >> 7;                   // / 128
        const int h = (int)(rest & (HO - 1));        // 0..255
        const long long bc = rest >> 8;              // 0..1023

        // input base: row 2h of channel bc, starting at element 4*w2
        const long long in_base = bc * (long long)(H_ * W_) + (long long)(2 * h) * W_ + 4 * w2;
        const float4 r0 = *reinterpret_cast<const float4*>(x + in_base);        // a0 b0 a1 b1
        const float4 r1 = *reinterpret_cast<const float4*>(x + in_base + W_);   // c0 d0 c1 d1

        const float a0 = r0.x, b0 = r0.y, a1 = r0.z, b1 = r0.w;
        const float c0 = r1.x, d0 = r1.y, c1 = r1.z, d1 = r1.w;

        float2 ll, lh, hl, hh;
        ll.x = (a0 + b0 + c0 + d0) * 0.5f;
        ll.y = (a1 + b1 + c1 + d1) * 0.5f;
        lh.x = (a0 - b0 + c0 - d0) * 0.5f;
        lh.y = (a1 - b1 + c1 - d1) * 0.5f;
        hl.x = (a0 + b0 - c0 - d0) * 0.5f;
        hl.y = (a1 + b1 - c1 - d1) * 0.5f;
        hh.x = (a0 - b0 - c0 + d0) * 0.5f;
        hh.y = (a1 - b1 - c1 + d1) * 0.5f;

        const long long out_base = bc * (long long)(HO * WO) + (long long)h * WO + 2 * w2;
        *reinterpret_cast<float2*>(out + out_base)               = ll;
        *reinterpret_cast<float2*>(out + out_base + 1LL*NPLANE)  = lh;
        *reinterpret_cast<float2*>(out + out_base + 2LL*NPLANE)  = hl;
        *reinterpret_cast<float2*>(out + out_base + 3LL*NPLANE)  = hh;
    }
}

extern "C" void kernel_launch(void* const* d_in, const int* in_sizes, int n_in,
                              void* d_out, int out_size, void* d_ws, size_t ws_size,
                              hipStream_t stream) {
    const float* x = (const float*)d_in[0];
    float* out = (float*)d_out;
    const int block = 256;
    const int grid = 2048;  // 256 CUs * 8 blocks/CU, grid-stride the rest
    haar_kernel<<<grid, block, 0, stream>>>(x, out);
}

// Round 3
// 429.808 us; speedup vs baseline: 1.0748x; 1.0748x over previous
//
#include <hip/hip_runtime.h>
#include <hip/hip_bf16.h>

// Haar wavelet transform: x (B=16, C=64, H=512, W=512) f32 ->
// 4 outputs (LL, LH, HL, HH), each (16, 64, 256, 256) f32, concatenated in d_out.
//
// R3: same as R2 but with clang ext_vector_type for nontemporal 16B stores
// (__builtin_nontemporal_store rejects HIP_vector_type structs).
// Each thread/iter: 2(h) x 8(w) input patch -> 4 independent 16B loads,
// 4 nontemporal 16B stores (one per plane). 32 exact iterations, unrolled.

#define B_ 16
#define C_ 64
#define H_ 512
#define W_ 512
#define HO (H_/2)
#define WO (W_/2)
#define NPLANE (B_*C_*HO*WO)          // 67,108,864 elements per output plane
#define W4 (WO/4)                     // 64 float4 per output row
#define NWORK (B_*C_*HO*W4)           // 16,777,216 work units
#define NTHREADS (2048*256)           // 524,288
#define NITER (NWORK/NTHREADS)        // 32, exact

typedef float f32x4 __attribute__((ext_vector_type(4)));

__global__ __launch_bounds__(256) void haar_kernel(const float* __restrict__ x,
                                                   float* __restrict__ out) {
    const int tid = blockIdx.x * 256 + threadIdx.x;   // 0..524287
#pragma unroll 4
    for (int it = 0; it < NITER; ++it) {
        const long long idx = (long long)tid + (long long)it * NTHREADS;
        // decompose: idx -> (bc, h, w4)
        const int w4 = (int)(idx & (W4 - 1));         // 0..63
        const long long rest = idx >> 6;
        const int h = (int)(rest & (HO - 1));         // 0..255
        const long long bc = rest >> 8;               // 0..1023

        const long long in_base = bc * (long long)(H_ * W_) + (long long)(2 * h) * W_ + 8 * w4;
        // 4 independent 16B loads: rows 2h, 2h+1, two adjacent float4 each
        const f32x4 r0a = *reinterpret_cast<const f32x4*>(x + in_base);
        const f32x4 r0b = *reinterpret_cast<const f32x4*>(x + in_base + 4);
        const f32x4 r1a = *reinterpret_cast<const f32x4*>(x + in_base + W_);
        const f32x4 r1b = *reinterpret_cast<const f32x4*>(x + in_base + W_ + 4);

        // pairs: (a,b) adjacent in row0, (c,d) adjacent in row1
        f32x4 ll, lh, hl, hh;
        ll[0] = (r0a[0] + r0a[1] + r1a[0] + r1a[1]) * 0.5f;
        ll[1] = (r0a[2] + r0a[3] + r1a[2] + r1a[3]) * 0.5f;
        ll[2] = (r0b[0] + r0b[1] + r1b[0] + r1b[1]) * 0.5f;
        ll[3] = (r0b[2] + r0b[3] + r1b[2] + r1b[3]) * 0.5f;

        lh[0] = (r0a[0] - r0a[1] + r1a[0] - r1a[1]) * 0.5f;
        lh[1] = (r0a[2] - r0a[3] + r1a[2] - r1a[3]) * 0.5f;
        lh[2] = (r0b[0] - r0b[1] + r1b[0] - r1b[1]) * 0.5f;
        lh[3] = (r0b[2] - r0b[3] + r1b[2] - r1b[3]) * 0.5f;

        hl[0] = (r0a[0] + r0a[1] - r1a[0] - r1a[1]) * 0.5f;
        hl[1] = (r0a[2] + r0a[3] - r1a[2] - r1a[3]) * 0.5f;
        hl[2] = (r0b[0] + r0b[1] - r1b[0] - r1b[1]) * 0.5f;
        hl[3] = (r0b[2] + r0b[3] - r1b[2] - r1b[3]) * 0.5f;

        hh[0] = (r0a[0] - r0a[1] - r1a[0] + r1a[1]) * 0.5f;
        hh[1] = (r0a[2] - r0a[3] - r1a[2] + r1a[3]) * 0.5f;
        hh[2] = (r0b[0] - r0b[1] - r1b[0] + r1b[1]) * 0.5f;
        hh[3] = (r0b[2] - r0b[3] - r1b[2] + r1b[3]) * 0.5f;

        const long long out_base = bc * (long long)(HO * WO) + (long long)h * WO + 4 * w4;
        __builtin_nontemporal_store(ll, reinterpret_cast<f32x4*>(out + out_base));
        __builtin_nontemporal_store(lh, reinterpret_cast<f32x4*>(out + out_base + 1LL * NPLANE));
        __builtin_nontemporal_store(hl, reinterpret_cast<f32x4*>(out + out_base + 2LL * NPLANE));
        __builtin_nontemporal_store(hh, reinterpret_cast<f32x4*>(out + out_base + 3LL * NPLANE));
    }
}

extern "C" void kernel_launch(void* const* d_in, const int* in_sizes, int n_in,
                              void* d_out, int out_size, void* d_ws, size_t ws_size,
                              hipStream_t stream) {
    const float* x = (const float*)d_in[0];
    float* out = (float*)d_out;
    haar_kernel<<<2048, 256, 0, stream>>>(x, out);
}